// Round 10
// baseline (355.922 us; speedup 1.0000x reference)
//
#include <hip/hip_runtime.h>
#include <math.h>

#define EPS 1e-10f
#define P1_BLOCKS 2048
#define P2_BLOCKS 2048
#define MAIN_BLOCK 256

// ---------------- streaming path (count-weighted, no big gathers) ----------
// ws layout:
//   int    count[N]                (N*4 B)          zeroed via hipMemsetAsync
//   int    g_lastpos               (at N*4, 64B pad) set to -1 via memset 0xFF
//   double partials[P2_BLOCKS*4]   cls, bbox, sigma, neg
//   int    pnpos[P2_BLOCKS]

// pass 1: build per-anchor counts; find last valid-array position with label==1
__global__ __launch_bounds__(MAIN_BLOCK) void pass1_count(
    const int* __restrict__ vidx,    // [V]
    const int* __restrict__ labels,  // [N]
    int V,
    int* __restrict__ count,         // [N]
    int* __restrict__ g_lastpos)
{
    int tid    = blockIdx.x * blockDim.x + threadIdx.x;
    int stride = gridDim.x * blockDim.x;
    int lastpos = -1;

    for (int i = tid; i < V; i += stride) {
        int idx = vidx[i];
        atomicAdd(&count[idx], 1);
        if (labels[idx] == 1) lastpos = i;   // i ascending per thread
    }

    // wave-64 max reduce, one atomic per wave
    for (int off = 32; off > 0; off >>= 1) {
        int lp = __shfl_down(lastpos, off);
        lastpos = lp > lastpos ? lp : lastpos;
    }
    if ((threadIdx.x & 63) == 0 && lastpos >= 0)
        atomicMax(g_lastpos, lastpos);
}

// pass 2: coalesced stream over ALL anchors, weighted by count
__global__ __launch_bounds__(MAIN_BLOCK) void pass2_stream(
    const float4* __restrict__ bbox,     // [N]
    const float2* __restrict__ logits,   // [N]
    const float4* __restrict__ sigma,    // [N]
    const float4* __restrict__ gt,       // [N]
    const int*    __restrict__ labels,   // [N]
    const int*    __restrict__ count,    // [N]
    int N,
    double* __restrict__ partials,       // [P2_BLOCKS*4]
    int* __restrict__ pnpos)             // [P2_BLOCKS]
{
    double cls_s = 0.0, bbox_s = 0.0, sig_s = 0.0, neg_s = 0.0;
    int npos = 0;

    int tid    = blockIdx.x * blockDim.x + threadIdx.x;
    int stride = gridDim.x * blockDim.x;

    for (int a = tid; a < N; a += stride) {
        int    c  = count[a];
        int    l  = labels[a];
        float2 lg = logits[a];
        float4 p  = bbox[a];
        float4 t  = gt[a];
        float4 s  = sigma[a];

        if (c == 0) continue;   // bytes already fetched; skip compute only
        double dc = (double)c;

        float l_p = l ? lg.y : lg.x;
        float l_o = l ? lg.x : lg.y;
        float d   = l_o - l_p;
        float closs = (d > 0.0f) ? (d + log1pf(expf(-d))) : log1pf(expf(d));
        cls_s += dc * (double)closs;

        float dx = p.x - t.x, dy = p.y - t.y, dz = p.z - t.z, dw = p.w - t.w;
        float i0 = 1.0f / (EPS + s.x);
        float i1 = 1.0f / (EPS + s.y);
        float i2 = 1.0f / (EPS + s.z);
        float i3 = 1.0f / (EPS + s.w);

        if (l == 1) {
            float per_bbox = 0.5f * dx * dx * i0 + 0.5f * dy * dy * i1
                           + 0.5f * dz * dz * i2 + 0.5f * dw * dw * i3;
            float per_sigma = 0.5f * (logf(EPS + s.x) + logf(EPS + s.y)
                                    + logf(EPS + s.z) + logf(EPS + s.w));
            bbox_s += dc * (double)per_bbox;
            sig_s  += dc * (double)per_sigma;
            npos   += c;
        } else {
            neg_s += dc * (double)(i0 + i1 + i2 + i3);
        }
    }

    for (int off = 32; off > 0; off >>= 1) {
        cls_s  += __shfl_down(cls_s,  off);
        bbox_s += __shfl_down(bbox_s, off);
        sig_s  += __shfl_down(sig_s,  off);
        neg_s  += __shfl_down(neg_s,  off);
        npos   += __shfl_down(npos,   off);
    }

    __shared__ double s_acc[4][4];
    __shared__ int    s_np[4];
    int wave = threadIdx.x >> 6;
    if ((threadIdx.x & 63) == 0) {
        s_acc[wave][0] = cls_s;
        s_acc[wave][1] = bbox_s;
        s_acc[wave][2] = sig_s;
        s_acc[wave][3] = neg_s;
        s_np[wave] = npos;
    }
    __syncthreads();
    if (threadIdx.x == 0) {
        double c = 0, b = 0, sg = 0, ng = 0;
        int np = 0;
        for (int w = 0; w < 4; ++w) {
            c  += s_acc[w][0];
            b  += s_acc[w][1];
            sg += s_acc[w][2];
            ng += s_acc[w][3];
            np += s_np[w];
        }
        partials[blockIdx.x * 4 + 0] = c;
        partials[blockIdx.x * 4 + 1] = b;
        partials[blockIdx.x * 4 + 2] = sg;
        partials[blockIdx.x * 4 + 3] = ng;
        pnpos[blockIdx.x] = np;
    }
}

__global__ __launch_bounds__(256) void finalize2_kernel(
    const double* __restrict__ partials,
    const int* __restrict__ pnpos,
    int nb,
    const int* __restrict__ g_lastpos,
    const int* __restrict__ vidx,
    const float4* __restrict__ bbox,
    const float4* __restrict__ gt,
    int V,
    float* __restrict__ out)
{
    double cls_s = 0.0, bbox_s = 0.0, sig_s = 0.0, neg_s = 0.0;
    int npos = 0;

    for (int i = threadIdx.x; i < nb; i += 256) {
        cls_s  += partials[i * 4 + 0];
        bbox_s += partials[i * 4 + 1];
        sig_s  += partials[i * 4 + 2];
        neg_s  += partials[i * 4 + 3];
        npos   += pnpos[i];
    }

    for (int off = 32; off > 0; off >>= 1) {
        cls_s  += __shfl_down(cls_s,  off);
        bbox_s += __shfl_down(bbox_s, off);
        sig_s  += __shfl_down(sig_s,  off);
        neg_s  += __shfl_down(neg_s,  off);
        npos   += __shfl_down(npos,   off);
    }

    __shared__ double s_acc[4][4];
    __shared__ int    s_np[4];
    int wave = threadIdx.x >> 6;
    if ((threadIdx.x & 63) == 0) {
        s_acc[wave][0] = cls_s;
        s_acc[wave][1] = bbox_s;
        s_acc[wave][2] = sig_s;
        s_acc[wave][3] = neg_s;
        s_np[wave] = npos;
    }
    __syncthreads();

    if (threadIdx.x == 0) {
        double c = 0, b = 0, sg = 0, ng = 0;
        int np = 0;
        for (int w = 0; w < 4; ++w) {
            c  += s_acc[w][0];
            b  += s_acc[w][1];
            sg += s_acc[w][2];
            ng += s_acc[w][3];
            np += s_np[w];
        }
        int lp = *g_lastpos;

        out[0] = (float)(c / (double)V);
        out[1] = (float)(b / (double)np);
        out[2] = (float)(sg / (double)np);
        out[3] = (float)(ng / (double)(V - np));

        float v4 = 0.0f;
        if (lp >= 0) {
            int idx = vidx[lp];
            float4 pp = bbox[idx];
            float4 tt = gt[idx];
            float ddx = pp.x - tt.x, ddy = pp.y - tt.y;
            float ddz = pp.z - tt.z, ddw = pp.w - tt.w;
            v4 = 0.5f * (ddx * ddx + ddy * ddy + ddz * ddz + ddw * ddw) / (float)np;
        }
        out[4] = v4;
    }
}

// ---------------- fallback: verified round-6 gather path --------------------
#define FB_BATCH 4
#define FB_MAX_BLOCKS 4096

__global__ __launch_bounds__(MAIN_BLOCK) void rpn_loss_main_fb(
    const float4* __restrict__ bbox, const float2* __restrict__ logits,
    const float4* __restrict__ sigma, const float4* __restrict__ gt,
    const int* __restrict__ labels, const int* __restrict__ vidx, int V,
    double* __restrict__ partials, int* __restrict__ pnpos, int* __restrict__ plastpos)
{
    double cls_s = 0.0, bbox_s = 0.0, sig_s = 0.0, neg_s = 0.0;
    int npos = 0, lastpos = -1;
    int base = blockIdx.x * (MAIN_BLOCK * FB_BATCH) + threadIdx.x;

    int idxs[FB_BATCH]; bool vld[FB_BATCH];
#pragma unroll
    for (int k = 0; k < FB_BATCH; ++k) {
        int i = base + k * MAIN_BLOCK;
        vld[k] = (i < V);
        idxs[k] = vld[k] ? vidx[i] : 0;
    }
    int lbl[FB_BATCH]; float2 lg[FB_BATCH]; float4 p[FB_BATCH], t[FB_BATCH], s[FB_BATCH];
#pragma unroll
    for (int k = 0; k < FB_BATCH; ++k) lbl[k] = labels[idxs[k]];
#pragma unroll
    for (int k = 0; k < FB_BATCH; ++k) lg[k] = logits[idxs[k]];
#pragma unroll
    for (int k = 0; k < FB_BATCH; ++k) p[k] = bbox[idxs[k]];
#pragma unroll
    for (int k = 0; k < FB_BATCH; ++k) t[k] = gt[idxs[k]];
#pragma unroll
    for (int k = 0; k < FB_BATCH; ++k) s[k] = sigma[idxs[k]];

#pragma unroll
    for (int k = 0; k < FB_BATCH; ++k) {
        if (!vld[k]) continue;
        float l_p = lbl[k] ? lg[k].y : lg[k].x;
        float l_o = lbl[k] ? lg[k].x : lg[k].y;
        float d = l_o - l_p;
        float closs = (d > 0.0f) ? (d + log1pf(expf(-d))) : log1pf(expf(d));
        cls_s += (double)closs;
        float dx = p[k].x - t[k].x, dy = p[k].y - t[k].y;
        float dz = p[k].z - t[k].z, dw = p[k].w - t[k].w;
        float i0 = 1.0f / (EPS + s[k].x), i1 = 1.0f / (EPS + s[k].y);
        float i2 = 1.0f / (EPS + s[k].z), i3 = 1.0f / (EPS + s[k].w);
        if (lbl[k] == 1) {
            bbox_s += (double)(0.5f * dx * dx * i0 + 0.5f * dy * dy * i1
                             + 0.5f * dz * dz * i2 + 0.5f * dw * dw * i3);
            sig_s += (double)(0.5f * (logf(EPS + s[k].x) + logf(EPS + s[k].y)
                                    + logf(EPS + s[k].z) + logf(EPS + s[k].w)));
            npos += 1;
            lastpos = base + k * MAIN_BLOCK;
        } else {
            neg_s += (double)(i0 + i1 + i2 + i3);
        }
    }

    for (int off = 32; off > 0; off >>= 1) {
        cls_s += __shfl_down(cls_s, off); bbox_s += __shfl_down(bbox_s, off);
        sig_s += __shfl_down(sig_s, off); neg_s += __shfl_down(neg_s, off);
        npos += __shfl_down(npos, off);
        int lp = __shfl_down(lastpos, off);
        lastpos = lp > lastpos ? lp : lastpos;
    }
    __shared__ double s_acc[4][4]; __shared__ int s_np[4]; __shared__ int s_lp[4];
    int wave = threadIdx.x >> 6;
    if ((threadIdx.x & 63) == 0) {
        s_acc[wave][0] = cls_s; s_acc[wave][1] = bbox_s;
        s_acc[wave][2] = sig_s; s_acc[wave][3] = neg_s;
        s_np[wave] = npos; s_lp[wave] = lastpos;
    }
    __syncthreads();
    if (threadIdx.x == 0) {
        double c = 0, b = 0, sg = 0, ng = 0; int np = 0, lp = -1;
        for (int w = 0; w < 4; ++w) {
            c += s_acc[w][0]; b += s_acc[w][1]; sg += s_acc[w][2]; ng += s_acc[w][3];
            np += s_np[w]; lp = s_lp[w] > lp ? s_lp[w] : lp;
        }
        partials[blockIdx.x * 4 + 0] = c; partials[blockIdx.x * 4 + 1] = b;
        partials[blockIdx.x * 4 + 2] = sg; partials[blockIdx.x * 4 + 3] = ng;
        pnpos[blockIdx.x] = np; plastpos[blockIdx.x] = lp;
    }
}

__global__ __launch_bounds__(256) void finalize_fb(
    const double* __restrict__ partials, const int* __restrict__ pnpos,
    const int* __restrict__ plastpos, int nb, const int* __restrict__ vidx,
    const float4* __restrict__ bbox, const float4* __restrict__ gt,
    int V, float* __restrict__ out)
{
    double cls_s = 0.0, bbox_s = 0.0, sig_s = 0.0, neg_s = 0.0;
    int npos = 0, lastpos = -1;
    for (int i = threadIdx.x; i < nb; i += 256) {
        cls_s += partials[i * 4 + 0]; bbox_s += partials[i * 4 + 1];
        sig_s += partials[i * 4 + 2]; neg_s += partials[i * 4 + 3];
        npos += pnpos[i];
        int lp = plastpos[i]; lastpos = lp > lastpos ? lp : lastpos;
    }
    for (int off = 32; off > 0; off >>= 1) {
        cls_s += __shfl_down(cls_s, off); bbox_s += __shfl_down(bbox_s, off);
        sig_s += __shfl_down(sig_s, off); neg_s += __shfl_down(neg_s, off);
        npos += __shfl_down(npos, off);
        int lp = __shfl_down(lastpos, off);
        lastpos = lp > lastpos ? lp : lastpos;
    }
    __shared__ double s_acc[4][4]; __shared__ int s_np[4]; __shared__ int s_lp[4];
    int wave = threadIdx.x >> 6;
    if ((threadIdx.x & 63) == 0) {
        s_acc[wave][0] = cls_s; s_acc[wave][1] = bbox_s;
        s_acc[wave][2] = sig_s; s_acc[wave][3] = neg_s;
        s_np[wave] = npos; s_lp[wave] = lastpos;
    }
    __syncthreads();
    if (threadIdx.x == 0) {
        double c = 0, b = 0, sg = 0, ng = 0; int np = 0, lp = -1;
        for (int w = 0; w < 4; ++w) {
            c += s_acc[w][0]; b += s_acc[w][1]; sg += s_acc[w][2]; ng += s_acc[w][3];
            np += s_np[w]; lp = s_lp[w] > lp ? s_lp[w] : lp;
        }
        out[0] = (float)(c / (double)V);
        out[1] = (float)(b / (double)np);
        out[2] = (float)(sg / (double)np);
        out[3] = (float)(ng / (double)(V - np));
        float v4 = 0.0f;
        if (lp >= 0) {
            int idx = vidx[lp];
            float4 pp = bbox[idx]; float4 tt = gt[idx];
            float ddx = pp.x - tt.x, ddy = pp.y - tt.y;
            float ddz = pp.z - tt.z, ddw = pp.w - tt.w;
            v4 = 0.5f * (ddx * ddx + ddy * ddy + ddz * ddz + ddw * ddw) / (float)np;
        }
        out[4] = v4;
    }
}

extern "C" void kernel_launch(void* const* d_in, const int* in_sizes, int n_in,
                              void* d_out, int out_size, void* d_ws, size_t ws_size,
                              hipStream_t stream) {
    const float* bbox_pred    = (const float*)d_in[0];  // [1, N, 4]
    const float* class_logits = (const float*)d_in[1];  // [1, N, 2]
    const float* sigma_pred   = (const float*)d_in[2];  // [1, N, 4]
    const float* gt_bbox      = (const float*)d_in[3];  // [1, N, 4]
    const int*   gt_label     = (const int*)d_in[4];    // [1, N]
    const int*   valid_idx    = (const int*)d_in[5];    // [V]

    int N = in_sizes[4];
    int V = in_sizes[5];

    size_t count_bytes = (size_t)N * sizeof(int);
    size_t need = count_bytes + 64
                + (size_t)P2_BLOCKS * 4 * sizeof(double)
                + (size_t)P2_BLOCKS * sizeof(int);

    if (ws_size >= need) {
        // ---------------- streaming path ----------------
        int*    count     = (int*)d_ws;
        char*   base      = (char*)d_ws + count_bytes;
        int*    g_lastpos = (int*)base;                       // 4 B (64B slot)
        double* partials  = (double*)(base + 64);
        int*    pnpos     = (int*)(base + 64 + P2_BLOCKS * 4 * sizeof(double));

        hipMemsetAsync(count, 0, count_bytes, stream);
        hipMemsetAsync(g_lastpos, 0xFF, sizeof(int), stream);  // -1

        pass1_count<<<P1_BLOCKS, MAIN_BLOCK, 0, stream>>>(
            valid_idx, gt_label, V, count, g_lastpos);

        pass2_stream<<<P2_BLOCKS, MAIN_BLOCK, 0, stream>>>(
            (const float4*)bbox_pred, (const float2*)class_logits,
            (const float4*)sigma_pred, (const float4*)gt_bbox,
            gt_label, count, N, partials, pnpos);

        finalize2_kernel<<<1, 256, 0, stream>>>(
            partials, pnpos, P2_BLOCKS, g_lastpos, valid_idx,
            (const float4*)bbox_pred, (const float4*)gt_bbox, V, (float*)d_out);
    } else {
        // ---------------- fallback: verified gather path ----------------
        double* partials = (double*)d_ws;
        int*    pnpos    = (int*)((char*)d_ws + FB_MAX_BLOCKS * 4 * sizeof(double));
        int*    plastpos = pnpos + FB_MAX_BLOCKS;

        int blocks = (V + MAIN_BLOCK * FB_BATCH - 1) / (MAIN_BLOCK * FB_BATCH);
        if (blocks > FB_MAX_BLOCKS) blocks = FB_MAX_BLOCKS;

        rpn_loss_main_fb<<<blocks, MAIN_BLOCK, 0, stream>>>(
            (const float4*)bbox_pred, (const float2*)class_logits,
            (const float4*)sigma_pred, (const float4*)gt_bbox,
            gt_label, valid_idx, V, partials, pnpos, plastpos);

        finalize_fb<<<1, 256, 0, stream>>>(
            partials, pnpos, plastpos, blocks, valid_idx,
            (const float4*)bbox_pred, (const float4*)gt_bbox, V, (float*)d_out);
    }
}